// Round 12
// baseline (4231.409 us; speedup 1.0000x reference)
//
#include <hip/hip_runtime.h>
#include <stdint.h>

#pragma clang fp contract(off)

#define T_STEPS 784
#define NH 64
#define NOUT 10

typedef __attribute__((ext_vector_type(2))) float f32x2;
typedef __attribute__((ext_vector_type(4))) float f32x4;

// v_pk_fma_f32 macros: verified bit-exact in rounds 8/9 (absmax 9.77e-4).
// PK_LO: both halves multiply by wp.lo (k=2g); PK_HI: by wp.hi (k=2g+1).
#define PK_LO(acc, s, wp) \
    asm("v_pk_fma_f32 %0, %1, %2, %0 op_sel:[0,0,0] op_sel_hi:[1,0,1]" \
        : "+v"(acc) : "v"(s), "v"(wp))
#define PK_HI(acc, s, wp) \
    asm("v_pk_fma_f32 %0, %1, %2, %0 op_sel:[0,1,0] op_sel_hi:[1,1,1]" \
        : "+v"(acc) : "v"(s), "v"(wp))

// th = (th + mem*co) - ((th-0.5)*0.02), each op rounded, old mem  (r3-verified)
#define THUP(tt, mm) { const float p_ = (mm) * co; const float q_ = (tt) + p_; \
    const float r_ = (tt) - 0.5f; const float rs_ = r_ * 0.02f; (tt) = q_ - rs_; }
// mem = (spike ? 0 : mem*0.5) + h   (r3-verified)
#define MEMUP(mm, ss, hh) { const float md_ = (mm) * 0.5f; \
    const float keep_ = (ss) ? 0.0f : md_; (mm) = keep_ + (hh); }

// Producer/consumer: block = 2 waves, 4 batch rows per block, lane = neuron j.
// wave0: layer1+layer2 (weights = W2 rows), writes s2 spikes to double-buffered LDS.
// wave1: layer3 (weights = W3 rows) one step behind + spike counts + epilogue.
// The weight register block wp[32] is SHARED between waves (loaded from W2 or W3
// per wave id), as is the layer state (mX/tX/sX) -> per-wave footprint ~128 regs
// -> 3-4 waves/SIMD instead of the 2-wave cap of rounds 8-11.

__global__ __attribute__((amdgpu_flat_work_group_size(128, 128)))
__attribute__((amdgpu_waves_per_eu(3, 4)))
void tesnn_main_kernel(
    const float* __restrict__ input,
    const float* __restrict__ W1, const float* __restrict__ b1,
    const float* __restrict__ W2, const float* __restrict__ b2,
    const float* __restrict__ W3, const float* __restrict__ b3,
    const float* __restrict__ Wo, const float* __restrict__ bo,
    const float* __restrict__ ce,
    float* __restrict__ out, int N)
{
    __shared__ alignas(16) f32x2 sAB1[NH];        // wave0-internal s1 {a,b}
    __shared__ alignas(16) f32x2 sCD1[NH];        // wave0-internal s1 {c,d}
    __shared__ alignas(16) f32x2 sAB2[2][NH];     // s2 export, double-buffered
    __shared__ alignas(16) f32x2 sCD2[2][NH];

    const int tid = threadIdx.x;
    const int wid = tid >> 6;
    const int lane = tid & 63;
    const int n0 = blockIdx.x * 4;
    if (n0 >= N) return;
    const int na = n0;
    const int nb = (n0 + 1 < N) ? n0 + 1 : N - 1;
    const int nc = (n0 + 2 < N) ? n0 + 2 : N - 1;
    const int nd = (n0 + 3 < N) ? n0 + 3 : N - 1;

    // ---- shared-allocation weights: W2 rows for wave0, W3 rows for wave1 ----
    const float* Wmine = (wid == 0) ? W2 : W3;
    f32x2 wp[32];
#pragma unroll
    for (int i = 0; i < 32; ++i)
        wp[i] = *reinterpret_cast<const f32x2*>(&Wmine[(size_t)lane * NH + 2 * i]);
    const float bbX = (wid == 0) ? b2[lane] : b3[lane];

    // wave0-only small weights
    const float w1 = W1[lane];
    const float bb1 = b1[lane];

    // ---- state ----
    // wave0: L1 state + (shared regs) L2 state.  wave1: (shared regs) L3 state.
    float m1a = 0.0f, t1a = 0.5f; bool s1a = false;
    float m1b = 0.0f, t1b = 0.5f; bool s1b = false;
    float m1c = 0.0f, t1c = 0.5f; bool s1c = false;
    float m1d = 0.0f, t1d = 0.5f; bool s1d = false;
    float mXa = 0.0f, tXa = 0.5f; bool sXa = false;   // L2 (wave0) / L3 (wave1)
    float mXb = 0.0f, tXb = 0.5f; bool sXb = false;
    float mXc = 0.0f, tXc = 0.5f; bool sXc = false;
    float mXd = 0.0f, tXd = 0.5f; bool sXd = false;
    float c3fa = 0.0f, c3fb = 0.0f, c3fc = 0.0f, c3fd = 0.0f;  // wave1 only

    const float* xra = input + (size_t)na * T_STEPS;
    const float* xrb = input + (size_t)nb * T_STEPS;
    const float* xrc = input + (size_t)nc * T_STEPS;
    const float* xrd = input + (size_t)nd * T_STEPS;
    const float* cerow = ce + (size_t)lane * T_STEPS;

    float xa_cur = xra[0], xb_cur = xrb[0], xc_cur = xrc[0], xd_cur = xrd[0];
    float co_cur = cerow[0];   // both waves start at t=0

#pragma unroll 1
    for (int i = 0; i <= T_STEPS; ++i) {
        const bool active = (wid == 0) ? (i < T_STEPS) : (i >= 1);
        if (active) {
            const int t = (wid == 0) ? i : (i - 1);
            const int tn = (t < T_STEPS - 1) ? (t + 1) : (T_STEPS - 1);
            const float co = co_cur;
            co_cur = cerow[tn];               // prefetch for next active iter

            if (wid == 0) {
                // ---------- layer 1 (4 rows) ----------
                const float xa = xa_cur, xb = xb_cur, xc = xc_cur, xd = xd_cur;
                xa_cur = xra[tn]; xb_cur = xrb[tn]; xc_cur = xrc[tn]; xd_cur = xrd[tn];
                THUP(t1a, m1a) THUP(t1b, m1b) THUP(t1c, m1c) THUP(t1d, m1d)
                const float ha = (xa * w1) + bb1; MEMUP(m1a, s1a, ha)
                const float hb = (xb * w1) + bb1; MEMUP(m1b, s1b, hb)
                const float hc = (xc * w1) + bb1; MEMUP(m1c, s1c, hc)
                const float hd = (xd * w1) + bb1; MEMUP(m1d, s1d, hd)
                const bool p1a = m1a > t1a; s1a = p1a;
                const bool p1b = m1b > t1b; s1b = p1b;
                const bool p1c = m1c > t1c; s1c = p1c;
                const bool p1d = m1d > t1d; s1d = p1d;
                f32x2 vab; vab.x = p1a ? 1.0f : 0.0f; vab.y = p1b ? 1.0f : 0.0f;
                f32x2 vcd; vcd.x = p1c ? 1.0f : 0.0f; vcd.y = p1d ? 1.0f : 0.0f;
                sAB1[lane] = vab;             // ds_write_b64 (in-wave ordering)
                sCD1[lane] = vcd;
            }

            // ---------- shared: my layer's threshold + dot + mem update ----------
            THUP(tXa, mXa) THUP(tXb, mXb) THUP(tXc, mXc) THUP(tXd, mXd)

            const f32x2* rAB = (wid == 0) ? sAB1 : sAB2[(i + 1) & 1];
            const f32x2* rCD = (wid == 0) ? sCD1 : sCD2[(i + 1) & 1];
            f32x2 accAB; accAB.x = 0.0f; accAB.y = 0.0f;
            f32x2 accCD; accCD.x = 0.0f; accCD.y = 0.0f;
#pragma unroll
            for (int g = 0; g < 32; ++g) {
                const f32x4 qab = *reinterpret_cast<const f32x4*>(&rAB[2 * g]); // uniform b128
                const f32x4 qcd = *reinterpret_cast<const f32x4*>(&rCD[2 * g]);
                const f32x2 qab_lo = __builtin_shufflevector(qab, qab, 0, 1);   // k=2g
                const f32x2 qab_hi = __builtin_shufflevector(qab, qab, 2, 3);   // k=2g+1
                const f32x2 qcd_lo = __builtin_shufflevector(qcd, qcd, 0, 1);
                const f32x2 qcd_hi = __builtin_shufflevector(qcd, qcd, 2, 3);
                PK_LO(accAB, qab_lo, wp[g]);
                PK_HI(accAB, qab_hi, wp[g]);
                PK_LO(accCD, qcd_lo, wp[g]);
                PK_HI(accCD, qcd_hi, wp[g]);
            }
            const float hXa = accAB.x + bbX; MEMUP(mXa, sXa, hXa)
            const float hXb = accAB.y + bbX; MEMUP(mXb, sXb, hXb)
            const float hXc = accCD.x + bbX; MEMUP(mXc, sXc, hXc)
            const float hXd = accCD.y + bbX; MEMUP(mXd, sXd, hXd)
            const bool pXa = mXa > tXa; sXa = pXa;
            const bool pXb = mXb > tXb; sXb = pXb;
            const bool pXc = mXc > tXc; sXc = pXc;
            const bool pXd = mXd > tXd; sXd = pXd;

            if (wid == 0) {
                // export s2 spikes for wave1 (read next iteration, after barrier)
                f32x2 vab; vab.x = pXa ? 1.0f : 0.0f; vab.y = pXb ? 1.0f : 0.0f;
                f32x2 vcd; vcd.x = pXc ? 1.0f : 0.0f; vcd.y = pXd ? 1.0f : 0.0f;
                sAB2[i & 1][lane] = vab;
                sCD2[i & 1][lane] = vcd;
            } else {
                c3fa += pXa ? 1.0f : 0.0f;
                c3fb += pXb ? 1.0f : 0.0f;
                c3fc += pXc ? 1.0f : 0.0f;
                c3fd += pXd ? 1.0f : 0.0f;
            }
        }
        __syncthreads();
    }

    // ---- epilogue (wave1): out[n][o] = (sum_t s3) @ Wo.T / T + bo ----
    if (wid == 1) {
        const double cA = (double)c3fa, cB = (double)c3fb;
        const double cC = (double)c3fc, cD = (double)c3fd;
        double rA = 0.0, rB = 0.0, rC = 0.0, rD = 0.0;
#pragma unroll
        for (int o = 0; o < NOUT; ++o) {
            const double wo = (double)Wo[o * NH + lane];
            double vA = cA * wo, vB = cB * wo, vC = cC * wo, vD = cD * wo;
#pragma unroll
            for (int off = 32; off; off >>= 1) {
                vA += __shfl_xor(vA, off, 64);
                vB += __shfl_xor(vB, off, 64);
                vC += __shfl_xor(vC, off, 64);
                vD += __shfl_xor(vD, off, 64);
            }
            if (lane == o) { rA = vA; rB = vB; rC = vC; rD = vD; }
        }
        if (lane < NOUT) {
            const double bod = (double)bo[lane];
            out[(size_t)na * NOUT + lane] = (float)(rA / (double)T_STEPS + bod);
            if (n0 + 1 < N) out[(size_t)nb * NOUT + lane] = (float)(rB / (double)T_STEPS + bod);
            if (n0 + 2 < N) out[(size_t)nc * NOUT + lane] = (float)(rC / (double)T_STEPS + bod);
            if (n0 + 3 < N) out[(size_t)nd * NOUT + lane] = (float)(rD / (double)T_STEPS + bod);
        }
    }
}

extern "C" void kernel_launch(void* const* d_in, const int* in_sizes, int n_in,
                              void* d_out, int out_size, void* d_ws, size_t ws_size,
                              hipStream_t stream) {
    const float* input = (const float*)d_in[0];
    const float* W1 = (const float*)d_in[1];
    const float* b1 = (const float*)d_in[2];
    const float* W2 = (const float*)d_in[3];
    const float* b2 = (const float*)d_in[4];
    const float* W3 = (const float*)d_in[5];
    const float* b3 = (const float*)d_in[6];
    const float* Wo = (const float*)d_in[7];
    const float* bo = (const float*)d_in[8];
    const float* ce = (const float*)d_in[9];
    float* out = (float*)d_out;

    const int N = in_sizes[0] / T_STEPS;

    hipLaunchKernelGGL(tesnn_main_kernel,
                       dim3((N + 3) / 4), dim3(128), 0, stream,
                       input, W1, b1, W2, b2, W3, b3, Wo, bo, ce, out, N);
}

// Round 16
// 3452.200 us; speedup vs baseline: 1.2257x; 1.2257x over previous
//
#include <hip/hip_runtime.h>
#include <stdint.h>

#pragma clang fp contract(off)

#define T_STEPS 784
#define NH 64
#define NOUT 10

typedef __attribute__((ext_vector_type(2))) float f32x2;
typedef __attribute__((ext_vector_type(4))) float f32x4;

// v_pk_fma_f32: per-half independent IEEE-rn f32 fma (verified bit-exact r8/r9/r12).
// PK_LO: both halves multiply by wp.lo (k=2g); PK_HI: by wp.hi (k=2g+1).
#define PK_LO(acc, s, wp) \
    asm("v_pk_fma_f32 %0, %1, %2, %0 op_sel:[0,0,0] op_sel_hi:[1,0,1]" \
        : "+v"(acc) : "v"(s), "v"(wp))
#define PK_HI(acc, s, wp) \
    asm("v_pk_fma_f32 %0, %1, %2, %0 op_sel:[0,1,0] op_sel_hi:[1,1,1]" \
        : "+v"(acc) : "v"(s), "v"(wp))

// th = (th + mem*co) - ((th-0.5)*0.02), each op rounded, old mem  (r3-verified)
#define THUP(tt, mm) { const float p_ = (mm) * co; const float q_ = (tt) + p_; \
    const float r_ = (tt) - 0.5f; const float rs_ = r_ * 0.02f; (tt) = q_ - rs_; }
// mem = (spike ? 0 : mem*0.5) + h   (r3-verified)
#define MEMUP(mm, ss, hh) { const float md_ = (mm) * 0.5f; \
    const float keep_ = (ss) ? 0.0f : md_; (mm) = keep_ + (hh); }

// Four batch rows per wave; lane = neuron j; no barriers (single-wave block).
// Spikes in LDS as two f32x2 arrays {a,b} / {c,d}; one uniform b128 read per
// array per g delivers k=2g,2g+1 for a row pair, and __builtin_shufflevector
// names the lo/hi register PAIRS of the load directly (no element movs) --
// they feed v_pk_fma_f32 straight from the load destination registers.

__global__ __attribute__((amdgpu_flat_work_group_size(64, 64)))
void tesnn_main_kernel(
    const float* __restrict__ input,
    const float* __restrict__ W1, const float* __restrict__ b1,
    const float* __restrict__ W2, const float* __restrict__ b2,
    const float* __restrict__ W3, const float* __restrict__ b3,
    const float* __restrict__ Wo, const float* __restrict__ bo,
    const float* __restrict__ ce,
    float* __restrict__ out, int N)
{
    __shared__ alignas(16) f32x2 sAB[NH];   // spikes {a,b}, reused L1->L2->L3
    __shared__ alignas(16) f32x2 sCD[NH];   // spikes {c,d}

    const int lane = threadIdx.x;
    const int n0 = blockIdx.x * 4;
    if (n0 >= N) return;
    const int na = n0;
    const int nb = (n0 + 1 < N) ? n0 + 1 : N - 1;
    const int nc = (n0 + 2 < N) ? n0 + 2 : N - 1;
    const int nd = (n0 + 3 < N) ? n0 + 3 : N - 1;

    // ---- per-lane weights (lane = neuron j) ----
    const float w1 = W1[lane];
    const float bb1 = b1[lane];
    const float bb2 = b2[lane];
    const float bb3 = b3[lane];

    f32x2 wp2[32], wp3[32];     // pairs {w[2g], w[2g+1]} of row j
#pragma unroll
    for (int i = 0; i < 32; ++i) {
        wp2[i] = *reinterpret_cast<const f32x2*>(&W2[(size_t)lane * NH + 2 * i]);
        wp3[i] = *reinterpret_cast<const f32x2*>(&W3[(size_t)lane * NH + 2 * i]);
    }

    // ---- state (scalar per row: a,b,c,d) ----
    float m1a = 0.0f, t1a = 0.5f; bool s1a = false;
    float m1b = 0.0f, t1b = 0.5f; bool s1b = false;
    float m1c = 0.0f, t1c = 0.5f; bool s1c = false;
    float m1d = 0.0f, t1d = 0.5f; bool s1d = false;
    float m2a = 0.0f, t2a = 0.5f; bool s2a = false;
    float m2b = 0.0f, t2b = 0.5f; bool s2b = false;
    float m2c = 0.0f, t2c = 0.5f; bool s2c = false;
    float m2d = 0.0f, t2d = 0.5f; bool s2d = false;
    float m3a = 0.0f, t3a = 0.5f; bool s3a = false;
    float m3b = 0.0f, t3b = 0.5f; bool s3b = false;
    float m3c = 0.0f, t3c = 0.5f; bool s3c = false;
    float m3d = 0.0f, t3d = 0.5f; bool s3d = false;
    float c3fa = 0.0f, c3fb = 0.0f, c3fc = 0.0f, c3fd = 0.0f;

    const float* xra = input + (size_t)na * T_STEPS;
    const float* xrb = input + (size_t)nb * T_STEPS;
    const float* xrc = input + (size_t)nc * T_STEPS;
    const float* xrd = input + (size_t)nd * T_STEPS;
    const float* cerow = ce + (size_t)lane * T_STEPS;    // ce is [H][T]

    float xa_cur = xra[0], xb_cur = xrb[0], xc_cur = xrc[0], xd_cur = xrd[0];
    float co_cur = cerow[0];

#pragma unroll 1
    for (int t = 0; t < T_STEPS; ++t) {
        const int tn = (t < T_STEPS - 1) ? (t + 1) : (T_STEPS - 1);
        const float xa_nxt = xra[tn];
        const float xb_nxt = xrb[tn];
        const float xc_nxt = xrc[tn];
        const float xd_nxt = xrd[tn];
        const float co_nxt = cerow[tn];

        const float xa = xa_cur, xb = xb_cur, xc = xc_cur, xd = xd_cur;
        const float co = co_cur;

        // ================= layer 1 =================
        THUP(t1a, m1a) THUP(t1b, m1b) THUP(t1c, m1c) THUP(t1d, m1d)
        {
            const float ha = (xa * w1) + bb1; MEMUP(m1a, s1a, ha)
            const float hb = (xb * w1) + bb1; MEMUP(m1b, s1b, hb)
            const float hc = (xc * w1) + bb1; MEMUP(m1c, s1c, hc)
            const float hd = (xd * w1) + bb1; MEMUP(m1d, s1d, hd)
        }
        const bool p1a = m1a > t1a; s1a = p1a;
        const bool p1b = m1b > t1b; s1b = p1b;
        const bool p1c = m1c > t1c; s1c = p1c;
        const bool p1d = m1d > t1d; s1d = p1d;
        {
            f32x2 vab; vab.x = p1a ? 1.0f : 0.0f; vab.y = p1b ? 1.0f : 0.0f;
            f32x2 vcd; vcd.x = p1c ? 1.0f : 0.0f; vcd.y = p1d ? 1.0f : 0.0f;
            sAB[lane] = vab;                 // ds_write_b64
            sCD[lane] = vcd;
        }

        // ================= layer 2 =================
        THUP(t2a, m2a) THUP(t2b, m2b) THUP(t2c, m2c) THUP(t2d, m2d)
        {
            f32x2 accAB; accAB.x = 0.0f; accAB.y = 0.0f;
            f32x2 accCD; accCD.x = 0.0f; accCD.y = 0.0f;
#pragma unroll
            for (int g = 0; g < 32; ++g) {
                const f32x4 qab = *reinterpret_cast<const f32x4*>(&sAB[2 * g]); // uniform b128
                const f32x4 qcd = *reinterpret_cast<const f32x4*>(&sCD[2 * g]);
                const f32x2 qab_lo = __builtin_shufflevector(qab, qab, 0, 1);   // k=2g
                const f32x2 qab_hi = __builtin_shufflevector(qab, qab, 2, 3);   // k=2g+1
                const f32x2 qcd_lo = __builtin_shufflevector(qcd, qcd, 0, 1);
                const f32x2 qcd_hi = __builtin_shufflevector(qcd, qcd, 2, 3);
                PK_LO(accAB, qab_lo, wp2[g]);
                PK_HI(accAB, qab_hi, wp2[g]);
                PK_LO(accCD, qcd_lo, wp2[g]);
                PK_HI(accCD, qcd_hi, wp2[g]);
            }
            const float h2a = accAB.x + bb2; MEMUP(m2a, s2a, h2a)
            const float h2b = accAB.y + bb2; MEMUP(m2b, s2b, h2b)
            const float h2c = accCD.x + bb2; MEMUP(m2c, s2c, h2c)
            const float h2d = accCD.y + bb2; MEMUP(m2d, s2d, h2d)
        }
        const bool p2a = m2a > t2a; s2a = p2a;
        const bool p2b = m2b > t2b; s2b = p2b;
        const bool p2c = m2c > t2c; s2c = p2c;
        const bool p2d = m2d > t2d; s2d = p2d;
        {
            f32x2 vab; vab.x = p2a ? 1.0f : 0.0f; vab.y = p2b ? 1.0f : 0.0f;
            f32x2 vcd; vcd.x = p2c ? 1.0f : 0.0f; vcd.y = p2d ? 1.0f : 0.0f;
            sAB[lane] = vab;                 // overwrite after all s1 reads done
            sCD[lane] = vcd;
        }

        // ================= layer 3 =================
        THUP(t3a, m3a) THUP(t3b, m3b) THUP(t3c, m3c) THUP(t3d, m3d)
        {
            f32x2 accAB; accAB.x = 0.0f; accAB.y = 0.0f;
            f32x2 accCD; accCD.x = 0.0f; accCD.y = 0.0f;
#pragma unroll
            for (int g = 0; g < 32; ++g) {
                const f32x4 qab = *reinterpret_cast<const f32x4*>(&sAB[2 * g]);
                const f32x4 qcd = *reinterpret_cast<const f32x4*>(&sCD[2 * g]);
                const f32x2 qab_lo = __builtin_shufflevector(qab, qab, 0, 1);
                const f32x2 qab_hi = __builtin_shufflevector(qab, qab, 2, 3);
                const f32x2 qcd_lo = __builtin_shufflevector(qcd, qcd, 0, 1);
                const f32x2 qcd_hi = __builtin_shufflevector(qcd, qcd, 2, 3);
                PK_LO(accAB, qab_lo, wp3[g]);
                PK_HI(accAB, qab_hi, wp3[g]);
                PK_LO(accCD, qcd_lo, wp3[g]);
                PK_HI(accCD, qcd_hi, wp3[g]);
            }
            const float h3a = accAB.x + bb3; MEMUP(m3a, s3a, h3a)
            const float h3b = accAB.y + bb3; MEMUP(m3b, s3b, h3b)
            const float h3c = accCD.x + bb3; MEMUP(m3c, s3c, h3c)
            const float h3d = accCD.y + bb3; MEMUP(m3d, s3d, h3d)
        }
        const bool p3a = m3a > t3a; s3a = p3a;
        const bool p3b = m3b > t3b; s3b = p3b;
        const bool p3c = m3c > t3c; s3c = p3c;
        const bool p3d = m3d > t3d; s3d = p3d;
        c3fa += p3a ? 1.0f : 0.0f;
        c3fb += p3b ? 1.0f : 0.0f;
        c3fc += p3c ? 1.0f : 0.0f;
        c3fd += p3d ? 1.0f : 0.0f;

        xa_cur = xa_nxt; xb_cur = xb_nxt; xc_cur = xc_nxt; xd_cur = xd_nxt;
        co_cur = co_nxt;
    }

    // ---- epilogue: out[n][o] = (sum_t s3) @ Wo.T / T + bo ----
    const double cA = (double)c3fa, cB = (double)c3fb;
    const double cC = (double)c3fc, cD = (double)c3fd;
    double rA = 0.0, rB = 0.0, rC = 0.0, rD = 0.0;
#pragma unroll
    for (int o = 0; o < NOUT; ++o) {
        const double wo = (double)Wo[o * NH + lane];
        double vA = cA * wo, vB = cB * wo, vC = cC * wo, vD = cD * wo;
#pragma unroll
        for (int off = 32; off; off >>= 1) {
            vA += __shfl_xor(vA, off, 64);
            vB += __shfl_xor(vB, off, 64);
            vC += __shfl_xor(vC, off, 64);
            vD += __shfl_xor(vD, off, 64);
        }
        if (lane == o) { rA = vA; rB = vB; rC = vC; rD = vD; }
    }
    if (lane < NOUT) {
        const double bod = (double)bo[lane];
        out[(size_t)na * NOUT + lane] = (float)(rA / (double)T_STEPS + bod);
        if (n0 + 1 < N) out[(size_t)nb * NOUT + lane] = (float)(rB / (double)T_STEPS + bod);
        if (n0 + 2 < N) out[(size_t)nc * NOUT + lane] = (float)(rC / (double)T_STEPS + bod);
        if (n0 + 3 < N) out[(size_t)nd * NOUT + lane] = (float)(rD / (double)T_STEPS + bod);
    }
}

extern "C" void kernel_launch(void* const* d_in, const int* in_sizes, int n_in,
                              void* d_out, int out_size, void* d_ws, size_t ws_size,
                              hipStream_t stream) {
    const float* input = (const float*)d_in[0];
    const float* W1 = (const float*)d_in[1];
    const float* b1 = (const float*)d_in[2];
    const float* W2 = (const float*)d_in[3];
    const float* b2 = (const float*)d_in[4];
    const float* W3 = (const float*)d_in[5];
    const float* b3 = (const float*)d_in[6];
    const float* Wo = (const float*)d_in[7];
    const float* bo = (const float*)d_in[8];
    const float* ce = (const float*)d_in[9];
    float* out = (float*)d_out;

    const int N = in_sizes[0] / T_STEPS;

    hipLaunchKernelGGL(tesnn_main_kernel,
                       dim3((N + 3) / 4), dim3(64), 0, stream,
                       input, W1, b1, W2, b2, W3, b3, Wo, bo, ce, out, N);
}